// Round 1
// baseline (333.194 us; speedup 1.0000x reference)
//
#include <hip/hip_runtime.h>
#include <hip/hip_bf16.h>

// Problem: B=32, F_IN=64, F_OUT=64, D=512, K=64
// out[(b,o),d] = sum_{k,e} T[(b,o),(k,e)] * W[k,e,d],
// T[(b,o),(k,e)] = sum_i coeff[o,i,k] * x[b,i,e]
// R10: np=1 8-wave block (128m x 512n), reg-staged Bs double-buffer with
// issue-early/write-late, raw s_barrier + counted waits (prefetch stays in
// flight across barriers), setprio. Grid 256 = mt(16) x ks(16), 1 block/CU.

#define KK 32768

typedef __attribute__((ext_vector_type(8))) short bf16x8;
typedef __attribute__((ext_vector_type(4))) float f32x4;

__device__ __forceinline__ unsigned short f2bf(float f) {
  unsigned int u = __float_as_uint(f);
  return (unsigned short)((u + 0x7FFFu + ((u >> 16) & 1u)) >> 16);  // RNE
}

__device__ __forceinline__ unsigned int pkbf2(float a, float b) {
  __hip_bfloat162 h = __float22bfloat162_rn(make_float2(a, b));  // v_cvt_pk_bf16_f32
  return *(unsigned int*)&h;
}

__device__ __forceinline__ void gld16(void* lds, const void* g) {
  __builtin_amdgcn_global_load_lds((const __attribute__((address_space(1))) void*)g,
                                   (__attribute__((address_space(3))) void*)lds,
                                   16, 0, 0);
}

// ---- convert W fp32 [64][512(e)][512(d)] -> WbT bf16 [512(d)][64*512 (k,e)]
__global__ __launch_bounds__(256) void convW(const float* __restrict__ W,
                                             unsigned short* __restrict__ WbT) {
  __shared__ float tile[64][65];
  int bx = blockIdx.x;                 // 64 k * 8 et * 8 dt = 4096
  int k = bx >> 6, et = (bx >> 3) & 7, dt = bx & 7;
  int t = threadIdx.x;
  const float* src = W + ((size_t)k * 512 + (size_t)et * 64) * 512 + dt * 64;
  int rr = t >> 6, cc = t & 63;
#pragma unroll
  for (int p = 0; p < 16; p++) {
    int e = p * 4 + rr;
    tile[e][cc] = src[(size_t)e * 512 + cc];
  }
  __syncthreads();
  int dl = t >> 4, eg = t & 15;
#pragma unroll
  for (int p = 0; p < 4; p++) {
    int d = p * 16 + dl;
    ushort4 v;
    v.x = f2bf(tile[eg * 4 + 0][d]);
    v.y = f2bf(tile[eg * 4 + 1][d]);
    v.z = f2bf(tile[eg * 4 + 2][d]);
    v.w = f2bf(tile[eg * 4 + 3][d]);
    *(ushort4*)(WbT + (size_t)(dt * 64 + d) * KK + k * 512 + et * 64 + eg * 4) = v;
  }
}

// ---- fused convX + convC (one launch)
__global__ __launch_bounds__(256) void convXC(const float* __restrict__ x,
                                              const float* __restrict__ c,
                                              unsigned short* __restrict__ xT,
                                              unsigned short* __restrict__ cb) {
  __shared__ unsigned short lds[64 * 130];
  int t = threadIdx.x;
  if (blockIdx.x < 128) {
    int bx = blockIdx.x;                // 32 b * 4 ec
    int b = bx >> 2, ec = bx & 3;
    const float* src = x + (size_t)b * 32768 + ec * 128;
#pragma unroll
    for (int j = 0; j < 32; j++) {
      int idx = j * 256 + t;            // 64 i x 128 e
      int i = idx >> 7, e = idx & 127;
      lds[i * 130 + e] = f2bf(src[(size_t)i * 512 + e]);
    }
    __syncthreads();
    unsigned short* dst = xT + (size_t)b * 32768 + ec * 128 * 64;
#pragma unroll
    for (int j = 0; j < 32; j++) {
      int idx = j * 256 + t;            // 128 e x 64 i
      int e = idx >> 6, i = idx & 63;
      dst[idx] = lds[i * 130 + e];
    }
  } else {
    int rb = blockIdx.x - 128;          // 64 blocks over r = o*64+i
    const float* src = c + (size_t)rb * 4096;
#pragma unroll
    for (int j = 0; j < 16; j++) {
      int idx = j * 256 + t;
      int r = idx >> 6, k = idx & 63;
      lds[r * 66 + k] = f2bf(src[idx]);
    }
    __syncthreads();
#pragma unroll
    for (int j = 0; j < 16; j++) {
      int idx = j * 256 + t;
      int k = idx >> 6, r = idx & 63;
      cb[(size_t)k * 4096 + rb * 64 + r] = lds[r * 66 + k];
    }
  }
}

// ---- fused T+GEMM v3 (R10): out[2048][512] += (coeff x)[m][kk] * WbT[n][kk]^T
// Grid 256 = mt(16) x ks(16); block-tile 128m x 512n, kk-slice 2048
// (4 k-words x 8 e-chunks of 64). 8 waves of 64m x 128n. T computed ONCE per
// block (np removed): total MFMA 77.3 GF. Bs (64 KB, per k-word) reg-staged:
// loads for step s+1 issue before step s's T-phase, ds_write after the
// post-main barrier -> no vmcnt drain at the mid barrier. xe dbuf'd (cross-ec
// gld16 prefetch), As separate. LDS 144 KB -> 1 block/CU, 2 waves/SIMD.
__global__ __launch_bounds__(512, 2) void fused_kern(const unsigned short* __restrict__ xT,
                                                     const unsigned short* __restrict__ cb,
                                                     const unsigned short* __restrict__ Bt,
                                                     float* __restrict__ out) {
  __shared__ unsigned short u2[2][8192];     // xe dbuf: [b_l*64+e_l][i 64], 2x16 KB
  __shared__ unsigned short As[8192];        // T tile [128 bo][64 kk-of-kw], 16 KB
  __shared__ unsigned short ck[16384];       // [4 kw][64 o][64 i], 32 KB
  __shared__ unsigned short Bs[32768];       // [512 d][64 kk-of-kw], 64 KB
  int bx = blockIdx.x;                       // ks minor: mt-siblings co-XCD (share Bt slice in L2)
  int ks = bx & 15, mt = bx >> 4;
  int m0 = mt * 128, kw0 = ks * 4, b0 = mt * 2;
  int t = threadIdx.x;
  int wid = t >> 6, lane = t & 63, q = lane >> 4, l16 = lane & 15;
  int wm = wid & 1;                          // m-half (= b index in T-phase)
  int wn = wid >> 1;                         // n-quarter (= o-tile in T-phase)
  int srow = t >> 3;                         // 0..63 staging row-in-round
  int sslot = t & 7;                         // phys 16B slot
  // ---- prologue: ck (once), xe(ec=0), Bs(s=0)
#pragma unroll
  for (int j = 0; j < 4; j++) {              // ck: row = kj*64 + o; row&7 == o&7
    int row = j * 64 + srow;
    int cg = sslot ^ (row & 7);
    gld16((char*)ck + (j * 512 + t) * 16,
          cb + (size_t)kw0 * 4096 + (size_t)row * 64 + cg * 8);
  }
#pragma unroll
  for (int j = 0; j < 2; j++) {              // xe(0): row = b_l*64 + e_l
    int row = j * 64 + srow;
    int cg = sslot ^ (row & 7);
    int bl = row >> 6, el = row & 63;
    gld16((char*)u2[0] + (j * 512 + t) * 16,
          xT + (size_t)(b0 + bl) * 32768 + (size_t)el * 64 + cg * 8);
  }
  uint4 pf[8];                               // Bs reg-stage (issue-early/write-late)
#pragma unroll
  for (int j = 0; j < 8; j++) {
    int row = j * 64 + srow;                 // row = d
    int cg = sslot ^ (row & 7);
    pf[j] = *(const uint4*)(Bt + (size_t)row * KK + (size_t)kw0 * 512 + cg * 8);
  }
#pragma unroll
  for (int j = 0; j < 8; j++)
    *(uint4*)(Bs + (size_t)(j * 512 + t) * 8) = pf[j];
  asm volatile("s_waitcnt vmcnt(0) lgkmcnt(0)" ::: "memory");
  __builtin_amdgcn_s_barrier();

  f32x4 acc[4][8] = {};                      // wave 64m x 128n
  bf16x8 ax[4][2];                           // A[m=e][k=i] frags, held per ec
#pragma unroll 1
  for (int s = 0; s < 32; s++) {             // steps: [ec 8][kw 4], kk=64 each
    int ec = s >> 2, kw = s & 3, ub = ec & 1;
    // B: issue prefetch for step s+1 (stays in flight across both barriers)
    if (s < 31) {
      int sn = s + 1, ecn = sn >> 2, kwn = sn & 3;
      size_t colb = (size_t)(kw0 + kwn) * 512 + (size_t)ecn * 64;
#pragma unroll
      for (int j = 0; j < 8; j++) {
        int row = j * 64 + srow;
        int cg = sslot ^ (row & 7);
        pf[j] = *(const uint4*)(Bt + (size_t)row * KK + colb + cg * 8);
      }
      if (kw == 3) {                         // xe(ec+1) -> other u2 buffer
#pragma unroll
        for (int j = 0; j < 2; j++) {
          int row = j * 64 + srow;
          int cg = sslot ^ (row & 7);
          int bl = row >> 6, el = row & 63;
          gld16((char*)u2[ub ^ 1] + (j * 512 + t) * 16,
                xT + (size_t)(b0 + bl) * 32768 + (size_t)((ec + 1) * 64 + el) * 64 + cg * 8);
        }
      }
    }
    // ax frags once per ec (u2[ub] ready via prev step's vmcnt(0)+barrier)
    if (kw == 0) {
#pragma unroll
      for (int et = 0; et < 4; et++)
#pragma unroll
        for (int k2 = 0; k2 < 2; k2++) {
          int row = wm * 64 + et * 16 + l16;
          int sz = (k2 * 4 + q) ^ (row & 7);
          ax[et][k2] = *(const bf16x8*)(&u2[ub][row * 64 + sz * 8]);
        }
    }
    // T-phase: this wave covers b = wm, o-tile = wn
    {
      const unsigned short* ckk = ck + kw * 4096;
      bf16x8 bc[2];
#pragma unroll
      for (int k2 = 0; k2 < 2; k2++) {
        int o = wn * 16 + l16;
        int sz = (k2 * 4 + q) ^ (o & 7);
        bc[k2] = *(const bf16x8*)(ckk + o * 64 + sz * 8);
      }
      f32x4 td[4] = {};                      // D[m=e][n=o]
      __builtin_amdgcn_s_setprio(1);
#pragma unroll
      for (int et = 0; et < 4; et++)
#pragma unroll
        for (int k2 = 0; k2 < 2; k2++)
          td[et] = __builtin_amdgcn_mfma_f32_16x16x32_bf16(ax[et][k2], bc[k2], td[et], 0, 0, 0);
      __builtin_amdgcn_s_setprio(0);
      // write As: row = wm*64 + wn*16 + l16 (bo), col c0 = et*16 + q*4 (e)
#pragma unroll
      for (int et = 0; et < 4; et++) {
        int row = wm * 64 + wn * 16 + l16;
        int c0 = et * 16 + q * 4;
        int phys = ((c0 >> 3) ^ (row & 7)) * 8 + (c0 & 7);
        uint2 v;
        v.x = pkbf2(td[et][0], td[et][1]);
        v.y = pkbf2(td[et][2], td[et][3]);
        *(uint2*)(As + row * 64 + phys) = v;
      }
    }
    // mid barrier: LDS-only wait; pf global loads stay outstanding
    asm volatile("s_waitcnt lgkmcnt(0)" ::: "memory");
    __builtin_amdgcn_sched_barrier(0);
    __builtin_amdgcn_s_barrier();
    // main: acc += As[wm..][kk] * Bs[wn..][kk]
#pragma unroll
    for (int k2 = 0; k2 < 2; k2++) {
      bf16x8 af[4], bfr[8];
#pragma unroll
      for (int mf = 0; mf < 4; mf++) {
        int row = wm * 64 + mf * 16 + l16;
        af[mf] = *(const bf16x8*)(As + row * 64 + (((k2 * 4 + q) ^ (row & 7))) * 8);
      }
#pragma unroll
      for (int nf = 0; nf < 8; nf++) {
        int row = wn * 128 + nf * 16 + l16;
        bfr[nf] = *(const bf16x8*)(Bs + row * 64 + (((k2 * 4 + q) ^ (row & 7))) * 8);
      }
      __builtin_amdgcn_s_setprio(1);
#pragma unroll
      for (int mf = 0; mf < 4; mf++)
#pragma unroll
        for (int nf = 0; nf < 8; nf++)
          acc[mf][nf] = __builtin_amdgcn_mfma_f32_16x16x32_bf16(af[mf], bfr[nf],
                                                                acc[mf][nf], 0, 0, 0);
      __builtin_amdgcn_s_setprio(0);
    }
    // post-main: wait prefetch regs, barrier (all waves done reading Bs/As),
    // then ds_write next Bs (visibility via next step's lgkmcnt+barrier)
    if (s < 31) {
      asm volatile("s_waitcnt vmcnt(0)" ::: "memory");
      __builtin_amdgcn_sched_barrier(0);
      __builtin_amdgcn_s_barrier();
#pragma unroll
      for (int j = 0; j < 8; j++)
        *(uint4*)(Bs + (size_t)(j * 512 + t) * 8) = pf[j];
    }
  }
#pragma unroll
  for (int mf = 0; mf < 4; mf++)
#pragma unroll
    for (int nf = 0; nf < 8; nf++)
#pragma unroll
      for (int r = 0; r < 4; r++)
        atomicAdd(&out[(size_t)(m0 + wm * 64 + mf * 16 + q * 4 + r) * 512
                       + wn * 128 + nf * 16 + l16],
                  acc[mf][nf][r]);
}

// ---- fp32 fallback (only if ws too small)
__global__ __launch_bounds__(256) void fallback_kern(const float* __restrict__ x,
                                                     const float* __restrict__ W,
                                                     const float* __restrict__ coeff,
                                                     float* __restrict__ out) {
  __shared__ float ev[64][129];
  int b = blockIdx.x >> 6, k = blockIdx.x & 63;
  int t = threadIdx.x, dl = t & 127, half = t >> 7;
  const float* xb = x + (size_t)b * 64 * 512;
  const float* Wk = W + (size_t)k * 512 * 512;
  for (int dc = 0; dc < 4; dc++) {
    int d = dc * 128 + dl;
    for (int i = half * 32; i < half * 32 + 32; i++) {
      float acc = 0.f;
      const float* xr = xb + (size_t)i * 512;
#pragma unroll 4
      for (int e = 0; e < 512; e++) acc += xr[e] * Wk[(size_t)e * 512 + d];
      ev[i][dl] = acc;
    }
    __syncthreads();
    for (int o = half * 32; o < half * 32 + 32; o++) {
      float s = 0.f;
#pragma unroll 8
      for (int i = 0; i < 64; i++) s += coeff[((size_t)o * 64 + i) * 64 + k] * ev[i][dl];
      atomicAdd(&out[((size_t)(b * 64 + o)) * 512 + d], s);
    }
    __syncthreads();
  }
}

extern "C" void kernel_launch(void* const* d_in, const int* in_sizes, int n_in,
                              void* d_out, int out_size, void* d_ws, size_t ws_size,
                              hipStream_t stream) {
  const float* x = (const float*)d_in[0];
  const float* W = (const float*)d_in[1];
  const float* coeff = (const float*)d_in[2];
  float* out = (float*)d_out;
  const size_t OFF_XT = 33554432;            // WbT: 512*32768*2
  const size_t OFF_CB = OFF_XT + 2097152;    // xT : 32*512*64*2
  const size_t NEED = OFF_CB + 524288;       // cb : 64*64*64*2

  hipMemsetAsync(d_out, 0, (size_t)out_size * sizeof(float), stream);
  if (ws_size >= NEED) {
    unsigned short* WbT = (unsigned short*)d_ws;
    unsigned short* xT  = (unsigned short*)((char*)d_ws + OFF_XT);
    unsigned short* cb  = (unsigned short*)((char*)d_ws + OFF_CB);
    convXC<<<192, 256, 0, stream>>>(x, coeff, xT, cb);
    convW<<<4096, 256, 0, stream>>>(W, WbT);
    fused_kern<<<256, 512, 0, stream>>>(xT, cb, WbT, out);
  } else {
    fallback_kern<<<2048, 256, 0, stream>>>(x, W, coeff, out);
  }
}

// Round 2
// 217.919 us; speedup vs baseline: 1.5290x; 1.5290x over previous
//
#include <hip/hip_runtime.h>
#include <hip/hip_bf16.h>

// Problem: B=32, F_IN=64, F_OUT=64, D=512, K=64
// out[(b,o),d] = sum_{k,e} T[(b,o),(k,e)] * W[k,e,d],
// T[(b,o),(k,e)] = sum_i coeff[o,i,k] * x[b,i,e]
// R11: fused_kern reverted to proven R9 (123 us). Preproc rewritten:
// single prep_kern, float4 loads + padded-LDS transpose + packed uint4
// bf16 stores (old convW was scalar-load/8B-store, convXC 2B stores).

#define KK 32768

typedef __attribute__((ext_vector_type(8))) short bf16x8;
typedef __attribute__((ext_vector_type(4))) float f32x4;

__device__ __forceinline__ unsigned short f2bf(float f) {
  unsigned int u = __float_as_uint(f);
  return (unsigned short)((u + 0x7FFFu + ((u >> 16) & 1u)) >> 16);  // RNE
}

__device__ __forceinline__ unsigned int pkbf2(float a, float b) {
  __hip_bfloat162 h = __float22bfloat162_rn(make_float2(a, b));  // v_cvt_pk_bf16_f32
  return *(unsigned int*)&h;
}

__device__ __forceinline__ void gld16(void* lds, const void* g) {
  __builtin_amdgcn_global_load_lds((const __attribute__((address_space(1))) void*)g,
                                   (__attribute__((address_space(3))) void*)lds,
                                   16, 0, 0);
}

// ---- merged preproc. Blocks:
//   [0,2048):    W fp32 [64 k][512 e][512 d] -> WbT bf16 [512 d][k*512+e]
//   [2048,2176): x fp32 [32 b][64 i][512 e]  -> xT bf16 [b][e][i] (ec chunks of 128)
//   [2176,2240): coeff fp32 [64 o][64 i][64 k] -> cb bf16 [k][o*64+i]
// LDS transpose, pad 133 (-> 2-way bank alias only = free). float4 in,
// uint4 (8 bf16 via v_cvt_pk_bf16_f32) out.
__global__ __launch_bounds__(256) void prep_kern(const float* __restrict__ x,
                                                 const float* __restrict__ c,
                                                 const float* __restrict__ W,
                                                 unsigned short* __restrict__ xT,
                                                 unsigned short* __restrict__ cb,
                                                 unsigned short* __restrict__ WbT) {
  __shared__ float tile[64][133];            // 34 KB
  int bx = blockIdx.x;
  int t = threadIdx.x;
  if (bx < 2048) {
    // ---- W part: block = (k, et, dq): 64 e-rows x 128 d-cols
    int k = bx >> 5, et = (bx >> 2) & 7, dq = bx & 3;
    const float* src = W + ((size_t)k * 512 + (size_t)et * 64) * 512 + dq * 128;
    int rr = t >> 5, c4 = t & 31;            // load: 64 rows x 32 float4
#pragma unroll
    for (int p = 0; p < 8; p++) {
      int e = p * 8 + rr;
      float4 v = *(const float4*)(src + (size_t)e * 512 + c4 * 4);
      *(float4*)&tile[e][c4 * 4] = v;
    }
    __syncthreads();
    // store: 128 d-rows x 8 e-chunks(8); lanes 0..7 = one d row (128 B contig)
    int ch = t & 7, dr = t >> 3;             // e0 = ch*8, d = p*32 + dr
#pragma unroll
    for (int p = 0; p < 4; p++) {
      int d = p * 32 + dr, e0 = ch * 8;
      uint4 o4;
      o4.x = pkbf2(tile[e0 + 0][d], tile[e0 + 1][d]);
      o4.y = pkbf2(tile[e0 + 2][d], tile[e0 + 3][d]);
      o4.z = pkbf2(tile[e0 + 4][d], tile[e0 + 5][d]);
      o4.w = pkbf2(tile[e0 + 6][d], tile[e0 + 7][d]);
      *(uint4*)(WbT + (size_t)(dq * 128 + d) * KK + k * 512 + et * 64 + e0) = o4;
    }
  } else if (bx < 2176) {
    // ---- x part: block = (b, ec): 64 i-rows x 128 e-cols -> xT[b][e][i]
    int bx2 = bx - 2048;
    int b = bx2 >> 2, ec = bx2 & 3;
    const float* src = x + (size_t)b * 32768 + ec * 128;
    int rr = t >> 5, c4 = t & 31;
#pragma unroll
    for (int p = 0; p < 8; p++) {
      int i = p * 8 + rr;
      float4 v = *(const float4*)(src + (size_t)i * 512 + c4 * 4);
      *(float4*)&tile[i][c4 * 4] = v;
    }
    __syncthreads();
    unsigned short* dst = xT + (size_t)b * 32768 + ec * 128 * 64;
    int ch = t & 7, er = t >> 3;             // i0 = ch*8, e = p*32 + er
#pragma unroll
    for (int p = 0; p < 4; p++) {
      int e = p * 32 + er, i0 = ch * 8;
      uint4 o4;
      o4.x = pkbf2(tile[i0 + 0][e], tile[i0 + 1][e]);
      o4.y = pkbf2(tile[i0 + 2][e], tile[i0 + 3][e]);
      o4.z = pkbf2(tile[i0 + 4][e], tile[i0 + 5][e]);
      o4.w = pkbf2(tile[i0 + 6][e], tile[i0 + 7][e]);
      *(uint4*)(dst + e * 64 + i0) = o4;
    }
  } else {
    // ---- coeff part (tiny, 1 MB): scalar transpose, r = o*64+i
    int rb = bx - 2176;
    unsigned short* lds = (unsigned short*)tile;
    const float* src = c + (size_t)rb * 4096;
#pragma unroll
    for (int j = 0; j < 16; j++) {
      int idx = j * 256 + t;
      int r = idx >> 6, k = idx & 63;
      lds[r * 66 + k] = f2bf(src[idx]);
    }
    __syncthreads();
#pragma unroll
    for (int j = 0; j < 16; j++) {
      int idx = j * 256 + t;
      int k = idx >> 6, r = idx & 63;
      cb[(size_t)k * 4096 + rb * 64 + r] = lds[r * 66 + k];
    }
  }
}

// ---- fused T+GEMM (R9, proven): out[2048][512] += (coeff x)[m][kk] * WbT[n][kk]^T
// Grid 512 = mt(16) x np(2) x ks(16); block-tile 128m x 256n, kk-slice 2048
// (4 k-words x 8 e-chunks of 64). 4 waves of 64m x 128n (+33% FLOP/LDS-byte
// vs 64x64). ck: all 4 k-words staged once per block. xe staged per ec,
// reused over 4 k-words; As aliases xe after ax extraction. LDS 80 KB ->
// 2 blocks/CU. T recompute x2 (np) -> 86 GF total MFMA.
__global__ __launch_bounds__(256, 2) void fused_kern(const unsigned short* __restrict__ xT,
                                                     const unsigned short* __restrict__ cb,
                                                     const unsigned short* __restrict__ Bt,
                                                     float* __restrict__ out) {
  __shared__ unsigned short u[128 * 64];     // xe (per-ec) / As (k-loop), 16 KB
  __shared__ unsigned short Bs[256 * 64];    // 32 KB
  __shared__ unsigned short ck[4 * 64 * 64]; // 32 KB (4 k-words, whole block)
  int bx = blockIdx.x;                       // [mt:4][np:1][ks:4]; mt-siblings co-XCD
  int ks = bx & 15, np = (bx >> 4) & 1, mt = bx >> 5;
  int m0 = mt * 128, n0 = np * 256, kw0 = ks * 4, b0 = mt * 2;
  int t = threadIdx.x;
  int wid = t >> 6, lane = t & 63, q = lane >> 4, l16 = lane & 15;
  int wmb = wid & 1;                         // m-half (also b index in T-phase)
  int wnh = wid >> 1;                        // n-half (also o-tile-pair in T-phase)
  int srow = t >> 3;                         // 0..31 staging row
  int cg = (t & 7) ^ (srow & 7);
  // block preamble: all 4 ck words (32 KB, 8 gld16 rounds)
  {
    const unsigned short* gc = cb + (size_t)kw0 * 4096;
#pragma unroll
    for (int j = 0; j < 8; j++) {
      int row = j * 32 + srow;               // row = kj*64 + o; row&7 == o&7
      gld16((char*)ck + (j * 256 + t) * 16, gc + (size_t)row * 64 + cg * 8);
    }
  }
  f32x4 acc[4][8] = {};                      // wave 64m x 128n
#pragma unroll 1
  for (int ec = 0; ec < 8; ec++) {
    // stage xe into u: row = b_l*64 + e_l
#pragma unroll
    for (int j = 0; j < 4; j++) {
      int row = j * 32 + srow;
      int bl = row >> 6, el = row & 63;
      gld16((char*)u + (j * 256 + t) * 16,
            xT + (size_t)(b0 + bl) * 32768 + (size_t)(ec * 64 + el) * 64 + cg * 8);
    }
    __syncthreads();                         // xe (+ck on ec=0) ready
    // ax frags: A[m=e][k=i] for this wave's b = wmb, all 4 e-tiles
    bf16x8 ax[4][2];
#pragma unroll
    for (int et = 0; et < 4; et++)
#pragma unroll
      for (int ks2 = 0; ks2 < 2; ks2++) {
        int row = wmb * 64 + et * 16 + l16;
        int s2 = (ks2 * 4 + q) ^ (row & 7);
        ax[et][ks2] = *(const bf16x8*)(u + row * 64 + s2 * 8);
      }
    __syncthreads();                         // ax reads done; u free for As
#pragma unroll 1
    for (int k = 0; k < 4; k++) {
      // stage Bs: 256 d-rows x 64 kk (32 KB, 8 rounds)
      const unsigned short* gb = Bt + (size_t)n0 * KK + (size_t)(kw0 + k) * 512 + ec * 64;
#pragma unroll
      for (int j = 0; j < 8; j++) {
        int row = j * 32 + srow;
        gld16((char*)Bs + (j * 256 + t) * 16, gb + (size_t)row * KK + cg * 8);
      }
      // T-phase: this wave covers b = wmb, o-tiles {wnh*2, wnh*2+1}
      const unsigned short* ckk = ck + k * 4096;
      bf16x8 bc[2][2];
#pragma unroll
      for (int otl = 0; otl < 2; otl++)
#pragma unroll
        for (int ks2 = 0; ks2 < 2; ks2++) {
          int o = (wnh * 2 + otl) * 16 + l16;
          int s2 = (ks2 * 4 + q) ^ (o & 7);
          bc[otl][ks2] = *(const bf16x8*)(ckk + o * 64 + s2 * 8);
        }
      f32x4 td[4][2] = {};                   // [et][otl], D[m=e][n=o]
#pragma unroll
      for (int et = 0; et < 4; et++)
#pragma unroll
        for (int otl = 0; otl < 2; otl++)
#pragma unroll
          for (int ks2 = 0; ks2 < 2; ks2++)
            td[et][otl] = __builtin_amdgcn_mfma_f32_16x16x32_bf16(ax[et][ks2], bc[otl][ks2],
                                                                  td[et][otl], 0, 0, 0);
      // write As (alias u): row = wmb*64 + ot*16 + l16 (o), col c0 = et*16 + q*4 (e)
#pragma unroll
      for (int et = 0; et < 4; et++)
#pragma unroll
        for (int otl = 0; otl < 2; otl++) {
          int row = wmb * 64 + (wnh * 2 + otl) * 16 + l16;
          int c0 = et * 16 + q * 4;
          int phys = ((c0 >> 3) ^ (row & 7)) * 8 + (c0 & 7);
          uint2 v;
          v.x = pkbf2(td[et][otl][0], td[et][otl][1]);
          v.y = pkbf2(td[et][otl][2], td[et][otl][3]);
          *(uint2*)(u + row * 64 + phys) = v;
        }
      __syncthreads();                       // mid: drains Bs gld16 + As ds_writes
      // main: acc += As[wm..][kk] * Bs[wn..][kk], wave 64m x 128n
#pragma unroll
      for (int ks2 = 0; ks2 < 2; ks2++) {
        bf16x8 af[4], bfr[8];
#pragma unroll
        for (int mf = 0; mf < 4; mf++) {
          int row = wmb * 64 + mf * 16 + l16;
          af[mf] = *(const bf16x8*)(u + row * 64 + (((ks2 * 4 + q) ^ (row & 7))) * 8);
        }
#pragma unroll
        for (int nf = 0; nf < 8; nf++) {
          int row = wnh * 128 + nf * 16 + l16;
          bfr[nf] = *(const bf16x8*)(Bs + row * 64 + (((ks2 * 4 + q) ^ (row & 7))) * 8);
        }
#pragma unroll
        for (int mf = 0; mf < 4; mf++)
#pragma unroll
          for (int nf = 0; nf < 8; nf++)
            acc[mf][nf] = __builtin_amdgcn_mfma_f32_16x16x32_bf16(af[mf], bfr[nf],
                                                                  acc[mf][nf], 0, 0, 0);
      }
      __syncthreads();                       // trailing: As/Bs free for rewrite
    }
  }
#pragma unroll
  for (int mf = 0; mf < 4; mf++)
#pragma unroll
    for (int nf = 0; nf < 8; nf++)
#pragma unroll
      for (int r = 0; r < 4; r++)
        atomicAdd(&out[(size_t)(m0 + wmb * 64 + mf * 16 + q * 4 + r) * 512
                       + n0 + wnh * 128 + nf * 16 + l16],
                  acc[mf][nf][r]);
}

// ---- fp32 fallback (only if ws too small)
__global__ __launch_bounds__(256) void fallback_kern(const float* __restrict__ x,
                                                     const float* __restrict__ W,
                                                     const float* __restrict__ coeff,
                                                     float* __restrict__ out) {
  __shared__ float ev[64][129];
  int b = blockIdx.x >> 6, k = blockIdx.x & 63;
  int t = threadIdx.x, dl = t & 127, half = t >> 7;
  const float* xb = x + (size_t)b * 64 * 512;
  const float* Wk = W + (size_t)k * 512 * 512;
  for (int dc = 0; dc < 4; dc++) {
    int d = dc * 128 + dl;
    for (int i = half * 32; i < half * 32 + 32; i++) {
      float acc = 0.f;
      const float* xr = xb + (size_t)i * 512;
#pragma unroll 4
      for (int e = 0; e < 512; e++) acc += xr[e] * Wk[(size_t)e * 512 + d];
      ev[i][dl] = acc;
    }
    __syncthreads();
    for (int o = half * 32; o < half * 32 + 32; o++) {
      float s = 0.f;
#pragma unroll 8
      for (int i = 0; i < 64; i++) s += coeff[((size_t)o * 64 + i) * 64 + k] * ev[i][dl];
      atomicAdd(&out[((size_t)(b * 64 + o)) * 512 + d], s);
    }
    __syncthreads();
  }
}

extern "C" void kernel_launch(void* const* d_in, const int* in_sizes, int n_in,
                              void* d_out, int out_size, void* d_ws, size_t ws_size,
                              hipStream_t stream) {
  const float* x = (const float*)d_in[0];
  const float* W = (const float*)d_in[1];
  const float* coeff = (const float*)d_in[2];
  float* out = (float*)d_out;
  const size_t OFF_XT = 33554432;            // WbT: 512*32768*2
  const size_t OFF_CB = OFF_XT + 2097152;    // xT : 32*512*64*2
  const size_t NEED = OFF_CB + 524288;       // cb : 64*64*64*2

  hipMemsetAsync(d_out, 0, (size_t)out_size * sizeof(float), stream);
  if (ws_size >= NEED) {
    unsigned short* WbT = (unsigned short*)d_ws;
    unsigned short* xT  = (unsigned short*)((char*)d_ws + OFF_XT);
    unsigned short* cb  = (unsigned short*)((char*)d_ws + OFF_CB);
    prep_kern<<<2240, 256, 0, stream>>>(x, coeff, W, xT, cb, WbT);
    fused_kern<<<512, 256, 0, stream>>>(xT, cb, WbT, out);
  } else {
    fallback_kern<<<2048, 256, 0, stream>>>(x, W, coeff, out);
  }
}